// Round 1
// baseline (388.586 us; speedup 1.0000x reference)
//
#include <hip/hip_runtime.h>

typedef __bf16 bf16x8 __attribute__((ext_vector_type(8)));
typedef float f32x4 __attribute__((ext_vector_type(4)));
typedef unsigned short u16;

#define B_ 2
#define T_ 2048
#define C_ 1024
#define H_ 16
#define D_ 64

__device__ __forceinline__ u16 f2bf(float f) {
    unsigned u = __builtin_bit_cast(unsigned, f);
    u += 0x7fffu + ((u >> 16) & 1u);
    return (u16)(u >> 16);
}

__device__ __forceinline__ f32x4 mfma16(bf16x8 a, bf16x8 b, f32x4 c) {
    return __builtin_amdgcn_mfma_f32_16x16x32_bf16(a, b, c, 0, 0, 0);
}

// ---------------- cast fp32 -> bf16 (same layout) ----------------
__global__ __launch_bounds__(256) void cast_kernel(const float* __restrict__ in,
                                                   u16* __restrict__ out, int n) {
    int i = (blockIdx.x * 256 + threadIdx.x) * 4;
    if (i < n) {
        float4 v = *(const float4*)(in + i);
        out[i + 0] = f2bf(v.x);
        out[i + 1] = f2bf(v.y);
        out[i + 2] = f2bf(v.z);
        out[i + 3] = f2bf(v.w);
    }
}

// ---------------- transpose + cast: in [K][N] fp32 -> out [N][K] bf16 ----------------
__global__ __launch_bounds__(256) void transpose_cast_kernel(const float* __restrict__ in,
                                                             u16* __restrict__ out,
                                                             int K, int N) {
    __shared__ float tile[64][65];
    int k0 = blockIdx.y * 64, n0 = blockIdx.x * 64;
    int t = threadIdx.x;
    int c = t & 63;
    int r0 = t >> 6;  // 0..3
    for (int i = 0; i < 16; ++i) {
        int r = r0 * 16 + i;
        tile[r][c] = in[(k0 + r) * N + n0 + c];
    }
    __syncthreads();
    for (int i = 0; i < 16; ++i) {
        int rn = r0 * 16 + i;           // n within tile
        out[(n0 + rn) * K + k0 + c] = f2bf(tile[c][rn]);  // c = k within tile (coalesced)
    }
}

// ---------------- GEMM: C[M,N] = A[M,K] * Bt[N,K]^T  (bf16 in, fp32 acc) ----------------
// MODE 1: qkv epilogue -> scatter to Q[b,h,t,d], K[b,h,t,d], Vt[b,h,d,t] (bf16)
// MODE 2: out epilogue -> Cout[m,n] = acc + bias[n] (fp32)
template <int MODE>
__global__ __launch_bounds__(256) void gemm_bt(const u16* __restrict__ A,
                                               const u16* __restrict__ Bt,
                                               float* __restrict__ Cout,
                                               u16* __restrict__ Qo, u16* __restrict__ Ko,
                                               u16* __restrict__ Vto,
                                               const float* __restrict__ bias,
                                               int M, int N, int K) {
    __shared__ __align__(16) u16 As[128 * 32];
    __shared__ __align__(16) u16 Bs[128 * 32];
    int m0 = blockIdx.y * 128, n0 = blockIdx.x * 128;
    int t = threadIdx.x;
    int wave = t >> 6, lane = t & 63, lr = lane & 15, quad = lane >> 4;
    int wm = (wave >> 1) * 64, wn = (wave & 1) * 64;

    f32x4 acc[4][4];
    for (int i = 0; i < 4; ++i)
        for (int j = 0; j < 4; ++j) acc[i][j] = (f32x4){0.f, 0.f, 0.f, 0.f};

    for (int kb = 0; kb < K; kb += 32) {
        // stage 128x32 A and 128x32 Bt tiles (16B per thread per chunk)
        for (int s = 0; s < 2; ++s) {
            int ch = t + s * 256;
            int row = ch >> 2, c8 = (ch & 3) * 8;
            *(uint4*)&As[row * 32 + c8] = *(const uint4*)&A[(m0 + row) * K + kb + c8];
            *(uint4*)&Bs[row * 32 + c8] = *(const uint4*)&Bt[(n0 + row) * K + kb + c8];
        }
        __syncthreads();
        bf16x8 af[4], bfr[4];
        for (int mt = 0; mt < 4; ++mt)
            af[mt] = *(const bf16x8*)&As[(wm + mt * 16 + lr) * 32 + quad * 8];
        for (int nt = 0; nt < 4; ++nt)
            bfr[nt] = *(const bf16x8*)&Bs[(wn + nt * 16 + lr) * 32 + quad * 8];
        for (int mt = 0; mt < 4; ++mt)
            for (int nt = 0; nt < 4; ++nt) acc[mt][nt] = mfma16(af[mt], bfr[nt], acc[mt][nt]);
        __syncthreads();
    }

    // epilogue: D[row=(quad*4+r), col=lr] per 16x16 tile
    for (int mt = 0; mt < 4; ++mt) {
        for (int nt = 0; nt < 4; ++nt) {
            for (int r = 0; r < 4; ++r) {
                int row = m0 + wm + mt * 16 + quad * 4 + r;
                int col = n0 + wn + nt * 16 + lr;
                float v = acc[mt][nt][r];
                if (MODE == 1) {
                    int part = col >> 10;       // 0:q 1:k 2:v
                    int rem = col & 1023;
                    int h = rem >> 6, d = rem & 63;
                    int b = row >> 11, tt = row & 2047;
                    int bh = b * H_ + h;
                    if (part == 0)      Qo[(bh * T_ + tt) * D_ + d] = f2bf(v);
                    else if (part == 1) Ko[(bh * T_ + tt) * D_ + d] = f2bf(v);
                    else                Vto[(bh * D_ + d) * T_ + tt] = f2bf(v);
                } else {
                    Cout[row * N + col] = v + bias[col];
                }
            }
        }
    }
}

// ---------------- flash attention (causal) ----------------
// grid: (B*H*T/64); block 256 = 4 waves; wave handles 16 q-rows.
// Q,K: [bh][t][d] bf16 ; Vt: [bh][d][t] bf16 ; Y: [b][t][h*64+d] bf16
__global__ __launch_bounds__(256) void attn_kernel(const u16* __restrict__ Q,
                                                   const u16* __restrict__ Kb,
                                                   const u16* __restrict__ Vt,
                                                   u16* __restrict__ Y) {
    __shared__ __align__(16) u16 P_lds[4][16 * 64];
    int qt = blockIdx.x & 31;
    int bh = blockIdx.x >> 5;
    int t = threadIdx.x, wave = t >> 6, lane = t & 63, lr = lane & 15, quad = lane >> 4;
    int qrow = qt * 64 + wave * 16;  // first q row of this wave

    const u16* qbase = Q + (bh * T_ + qrow + lr) * D_;
    bf16x8 qf0 = *(const bf16x8*)(qbase + quad * 8);
    bf16x8 qf1 = *(const bf16x8*)(qbase + 32 + quad * 8);

    float mrow[4], lrow[4];
    f32x4 oacc[4];
    for (int r = 0; r < 4; ++r) { mrow[r] = -INFINITY; lrow[r] = 0.f; }
    for (int dt = 0; dt < 4; ++dt) oacc[dt] = (f32x4){0.f, 0.f, 0.f, 0.f};

    u16* pl = &P_lds[wave][0];

    for (int kt = 0; kt <= qt; ++kt) {
        // S = Q K^T for 16 q-rows x 64 keys
        f32x4 sacc[4];
        for (int st = 0; st < 4; ++st) sacc[st] = (f32x4){0.f, 0.f, 0.f, 0.f};
        const u16* kbase = Kb + (bh * T_ + kt * 64) * D_;
        for (int st = 0; st < 4; ++st) {
            const u16* kp = kbase + (st * 16 + lr) * D_ + quad * 8;
            bf16x8 kf0 = *(const bf16x8*)(kp);
            bf16x8 kf1 = *(const bf16x8*)(kp + 32);
            sacc[st] = mfma16(qf0, kf0, sacc[st]);
            sacc[st] = mfma16(qf1, kf1, sacc[st]);
        }
        // scale + causal mask (only the diagonal tile needs masking)
        bool diag = (kt == qt);
        for (int st = 0; st < 4; ++st)
            for (int r = 0; r < 4; ++r) {
                float v = sacc[st][r] * 0.125f;
                if (diag && (kt * 64 + st * 16 + lr) > (qrow + quad * 4 + r)) v = -INFINITY;
                sacc[st][r] = v;
            }
        // online softmax per row (rows quad*4+r, replicated across 16 lanes of quad)
        float alpha[4];
        for (int r = 0; r < 4; ++r) {
            float v = fmaxf(fmaxf(sacc[0][r], sacc[1][r]), fmaxf(sacc[2][r], sacc[3][r]));
            for (int off = 8; off >= 1; off >>= 1) v = fmaxf(v, __shfl_xor(v, off, 16));
            float nm = fmaxf(mrow[r], v);
            alpha[r] = __expf(mrow[r] - nm);
            mrow[r] = nm;
            float rs = 0.f;
            for (int st = 0; st < 4; ++st) {
                float p = __expf(sacc[st][r] - nm);
                sacc[st][r] = p;
                rs += p;
            }
            for (int off = 8; off >= 1; off >>= 1) rs += __shfl_xor(rs, off, 16);
            lrow[r] = lrow[r] * alpha[r] + rs;
        }
        for (int dt = 0; dt < 4; ++dt)
            for (int r = 0; r < 4; ++r) oacc[dt][r] *= alpha[r];
        // write P (C-layout) to per-wave LDS, reread in A-layout (m120 transform)
        for (int st = 0; st < 4; ++st)
            for (int r = 0; r < 4; ++r)
                pl[(quad * 4 + r) * 64 + st * 16 + lr] = f2bf(sacc[st][r]);
        // per-wave LDS region + in-order per-wave LDS pipe: no barrier needed
        bf16x8 ap0 = *(const bf16x8*)&pl[lr * 64 + quad * 8];
        bf16x8 ap1 = *(const bf16x8*)&pl[lr * 64 + 32 + quad * 8];
        // O += P V  (B-fragment from Vt, k-contiguous)
        const u16* vbase = Vt + (bh * D_) * T_ + kt * 64;
        for (int dt = 0; dt < 4; ++dt) {
            const u16* vp = vbase + (dt * 16 + lr) * T_ + quad * 8;
            bf16x8 vf0 = *(const bf16x8*)(vp);
            bf16x8 vf1 = *(const bf16x8*)(vp + 32);
            oacc[dt] = mfma16(ap0, vf0, oacc[dt]);
            oacc[dt] = mfma16(ap1, vf1, oacc[dt]);
        }
    }

    // epilogue: Y[b, t, h*64 + d] bf16
    int b = bh >> 4, h = bh & 15;
    for (int dt = 0; dt < 4; ++dt)
        for (int r = 0; r < 4; ++r) {
            int tg = qrow + quad * 4 + r;
            float v = oacc[dt][r] / lrow[r];
            Y[(b * T_ + tg) * C_ + h * 64 + dt * 16 + lr] = f2bf(v);
        }
}

extern "C" void kernel_launch(void* const* d_in, const int* in_sizes, int n_in,
                              void* d_out, int out_size, void* d_ws, size_t ws_size,
                              hipStream_t stream) {
    const float* x      = (const float*)d_in[0];  // [B,T,C]
    const float* w_qkv  = (const float*)d_in[1];  // [C,3C]
    const float* w_proj = (const float*)d_in[2];  // [C,C]
    const float* b_proj = (const float*)d_in[3];  // [C]
    float* out = (float*)d_out;                   // [B,T,C] fp32

    char* ws = (char*)d_ws;
    // workspace layout (bytes)
    u16* x_bf    = (u16*)(ws + 0);          // 4096*1024*2 = 8 MB
    u16* wqkv_t  = (u16*)(ws + 8388608);    // 3072*1024*2 = 6 MB
    u16* wproj_t = (u16*)(ws + 14680064);   // 1024*1024*2 = 2 MB
    u16* q_bf    = (u16*)(ws + 16777216);   // 8 MB  [bh][t][d]
    u16* k_bf    = (u16*)(ws + 25165824);   // 8 MB  [bh][t][d]
    u16* vt_bf   = (u16*)(ws + 33554432);   // 8 MB  [bh][d][t]
    u16* y_bf    = (u16*)(ws + 41943040);   // 8 MB  [b*t][c]

    const int M = B_ * T_;  // 4096

    cast_kernel<<<M * C_ / 1024, 256, 0, stream>>>(x, x_bf, M * C_);
    transpose_cast_kernel<<<dim3(3 * C_ / 64, C_ / 64), 256, 0, stream>>>(w_qkv, wqkv_t, C_, 3 * C_);
    transpose_cast_kernel<<<dim3(C_ / 64, C_ / 64), 256, 0, stream>>>(w_proj, wproj_t, C_, C_);

    gemm_bt<1><<<dim3(3 * C_ / 128, M / 128), 256, 0, stream>>>(
        x_bf, wqkv_t, nullptr, q_bf, k_bf, vt_bf, nullptr, M, 3 * C_, C_);

    attn_kernel<<<B_ * H_ * (T_ / 64), 256, 0, stream>>>(q_bf, k_bf, vt_bf, y_bf);

    gemm_bt<2><<<dim3(C_ / 128, M / 128), 256, 0, stream>>>(
        y_bf, wproj_t, out, nullptr, nullptr, nullptr, b_proj, M, C_, C_);
}

// Round 2
// 221.893 us; speedup vs baseline: 1.7512x; 1.7512x over previous
//
#include <hip/hip_runtime.h>

typedef __bf16 bf16x8 __attribute__((ext_vector_type(8)));
typedef float f32x4 __attribute__((ext_vector_type(4)));
typedef unsigned short u16;

#define B_ 2
#define T_ 2048
#define C_ 1024
#define H_ 16
#define D_ 64

__device__ __forceinline__ u16 f2bf(float f) {
    unsigned u = __builtin_bit_cast(unsigned, f);
    u += 0x7fffu + ((u >> 16) & 1u);
    return (u16)(u >> 16);
}

__device__ __forceinline__ f32x4 mfma16(bf16x8 a, bf16x8 b, f32x4 c) {
    return __builtin_amdgcn_mfma_f32_16x16x32_bf16(a, b, c, 0, 0, 0);
}

// async global->LDS, 16B per lane; LDS dest = wave-uniform base + lane*16
__device__ __forceinline__ void gll16(const u16* g, u16* l) {
    __builtin_amdgcn_global_load_lds((const __attribute__((address_space(1))) unsigned int*)g,
                                     (__attribute__((address_space(3))) unsigned int*)l,
                                     16, 0, 0);
}

// ---------------- cast fp32 -> bf16 (same layout) ----------------
__global__ __launch_bounds__(256) void cast_kernel(const float* __restrict__ in,
                                                   u16* __restrict__ out, int n) {
    int i = (blockIdx.x * 256 + threadIdx.x) * 4;
    if (i < n) {
        float4 v = *(const float4*)(in + i);
        out[i + 0] = f2bf(v.x);
        out[i + 1] = f2bf(v.y);
        out[i + 2] = f2bf(v.z);
        out[i + 3] = f2bf(v.w);
    }
}

// ---------------- transpose + cast: in [K][N] fp32 -> out [N][K] bf16 ----------------
__global__ __launch_bounds__(256) void transpose_cast_kernel(const float* __restrict__ in,
                                                             u16* __restrict__ out,
                                                             int K, int N) {
    __shared__ float tile[64][65];
    int k0 = blockIdx.y * 64, n0 = blockIdx.x * 64;
    int t = threadIdx.x;
    int c = t & 63;
    int r0 = t >> 6;  // 0..3
    for (int i = 0; i < 16; ++i) {
        int r = r0 * 16 + i;
        tile[r][c] = in[(k0 + r) * N + n0 + c];
    }
    __syncthreads();
    for (int i = 0; i < 16; ++i) {
        int rn = r0 * 16 + i;
        out[(n0 + rn) * K + k0 + c] = f2bf(tile[c][rn]);
    }
}

// ---------------- GEMM: C[M,N] = A[M,K] * Bt[N,K]^T  (bf16 in, fp32 acc) ----------------
// LDS tiles 128x32 u16, group-swizzled: phys_group = group ^ (row&3)  (4 groups of 8 u16/row)
// MODE 1: qkv epilogue -> scatter to Q[bh,t,d], K[bh,t,d], Vt[bh,d,t] (bf16)
// MODE 2: out epilogue -> Cout[m,n] = acc + bias[n] (fp32)
template <int MODE>
__global__ __launch_bounds__(256) void gemm_bt(const u16* __restrict__ A,
                                               const u16* __restrict__ Bt,
                                               float* __restrict__ Cout,
                                               u16* __restrict__ Qo, u16* __restrict__ Ko,
                                               u16* __restrict__ Vto,
                                               const float* __restrict__ bias,
                                               int M, int N, int K) {
    __shared__ __align__(16) u16 As[128 * 32];
    __shared__ __align__(16) u16 Bs[128 * 32];
    int m0 = blockIdx.y * 128, n0 = blockIdx.x * 128;
    int t = threadIdx.x;
    int wave = t >> 6, lane = t & 63, lr = lane & 15, quad = lane >> 4;
    int wm = (wave >> 1) * 64, wn = (wave & 1) * 64;

    // staging mapping: 16 rows per instr, 4 lanes/row
    int srow = lane >> 2;            // 0..15
    int sgl = (lane & 3) ^ (srow & 3);  // logical group this lane fetches

    f32x4 acc[4][4];
    for (int i = 0; i < 4; ++i)
        for (int j = 0; j < 4; ++j) acc[i][j] = (f32x4){0.f, 0.f, 0.f, 0.f};

    int swz = (quad ^ (lr & 3)) * 8;  // phys byte-group offset for fragment reads

    for (int kb = 0; kb < K; kb += 32) {
        __syncthreads();  // previous compute done reading LDS
        for (int i = 0; i < 2; ++i) {
            int c = wave * 2 + i;          // chunk 0..7 (16 rows each)
            int row = c * 16 + srow;
            gll16(&A[(size_t)(m0 + row) * K + kb + sgl * 8], &As[c * 512]);
            gll16(&Bt[(size_t)(n0 + row) * K + kb + sgl * 8], &Bs[c * 512]);
        }
        __syncthreads();  // staging complete (vmcnt drained before barrier)
        bf16x8 af[4], bfr[4];
        for (int mt = 0; mt < 4; ++mt)
            af[mt] = *(const bf16x8*)&As[(wm + mt * 16 + lr) * 32 + swz];
        for (int nt = 0; nt < 4; ++nt)
            bfr[nt] = *(const bf16x8*)&Bs[(wn + nt * 16 + lr) * 32 + swz];
        for (int mt = 0; mt < 4; ++mt)
            for (int nt = 0; nt < 4; ++nt) acc[mt][nt] = mfma16(af[mt], bfr[nt], acc[mt][nt]);
    }

    // epilogue: D[row=(quad*4+r), col=lr] per 16x16 tile
    for (int mt = 0; mt < 4; ++mt) {
        for (int nt = 0; nt < 4; ++nt) {
            for (int r = 0; r < 4; ++r) {
                int row = m0 + wm + mt * 16 + quad * 4 + r;
                int col = n0 + wn + nt * 16 + lr;
                float v = acc[mt][nt][r];
                if (MODE == 1) {
                    int part = col >> 10;       // 0:q 1:k 2:v
                    int rem = col & 1023;
                    int h = rem >> 6, d = rem & 63;
                    int b = row >> 11, tt = row & 2047;
                    int bh = b * H_ + h;
                    if (part == 0)      Qo[((size_t)(bh * T_ + tt)) * D_ + d] = f2bf(v);
                    else if (part == 1) Ko[((size_t)(bh * T_ + tt)) * D_ + d] = f2bf(v);
                    else                Vto[((size_t)(bh * D_ + d)) * T_ + tt] = f2bf(v);
                } else {
                    Cout[(size_t)row * N + col] = v + bias[col];
                }
            }
        }
    }
}

// ---------------- flash attention (causal) ----------------
// grid 1024; heavy-first: qt = 31 - (blockIdx.x>>5). Block 256 = 4 waves, wave = 16 q-rows.
// K/V 64x64 tiles double-buffered in LDS via global_load_lds, group-swizzled
// (phys_group = group ^ (row&7), 8 groups of 8 u16 per 64-u16 row).
__global__ __launch_bounds__(256, 4) void attn_kernel(const u16* __restrict__ Q,
                                                      const u16* __restrict__ Kb,
                                                      const u16* __restrict__ Vt,
                                                      u16* __restrict__ Y) {
    __shared__ __align__(16) u16 Kls[2][64 * 64];
    __shared__ __align__(16) u16 Vls[2][64 * 64];
    __shared__ __align__(16) u16 Pls[4][16 * 64];
    int qt = 31 - (blockIdx.x >> 5);
    int bh = blockIdx.x & 31;
    int t = threadIdx.x, wave = t >> 6, lane = t & 63, lr = lane & 15, quad = lane >> 4;
    int qrow = qt * 64 + wave * 16;

    const u16* qbase = Q + ((size_t)bh * T_ + qrow + lr) * D_;
    bf16x8 qf0 = *(const bf16x8*)(qbase + quad * 8);
    bf16x8 qf1 = *(const bf16x8*)(qbase + 32 + quad * 8);

    // staging mapping: 8 rows per instr, 8 lanes/row
    int srow = lane >> 3;              // 0..7
    int sgl = (lane & 7) ^ srow;       // logical group this lane fetches
    const u16* kbase = Kb + (size_t)bh * T_ * D_;
    const u16* vbase = Vt + (size_t)bh * D_ * T_;

    float mrow[4], lrow[4];
    f32x4 oacc[4];
    for (int r = 0; r < 4; ++r) { mrow[r] = -INFINITY; lrow[r] = 0.f; }
    for (int dt = 0; dt < 4; ++dt) oacc[dt] = (f32x4){0.f, 0.f, 0.f, 0.f};

    u16* pl = &Pls[wave][0];
    int swz1 = (quad ^ (lr & 7)) * 8;        // phys offset, logical group = quad
    int swz2 = ((quad + 4) ^ (lr & 7)) * 8;  // phys offset, logical group = quad+4

    // prologue stage kt=0 into buf 0
    {
        for (int i = 0; i < 2; ++i) {
            int c = wave * 2 + i;
            int row = c * 8 + srow;
            gll16(kbase + (size_t)row * D_ + sgl * 8, &Kls[0][c * 512]);
            gll16(vbase + (size_t)row * T_ + sgl * 8, &Vls[0][c * 512]);
        }
    }

    for (int kt = 0; kt <= qt; ++kt) {
        int buf = kt & 1;
        __syncthreads();  // staging of buf done; everyone finished reading buf^1
        if (kt < qt) {
            int nk = kt + 1;
            for (int i = 0; i < 2; ++i) {
                int c = wave * 2 + i;
                int row = c * 8 + srow;
                gll16(kbase + (size_t)(nk * 64 + row) * D_ + sgl * 8, &Kls[buf ^ 1][c * 512]);
                gll16(vbase + (size_t)row * T_ + nk * 64 + sgl * 8, &Vls[buf ^ 1][c * 512]);
            }
        }
        // S = Q K^T (16 q-rows x 64 keys)
        f32x4 sacc[4];
        for (int st = 0; st < 4; ++st) sacc[st] = (f32x4){0.f, 0.f, 0.f, 0.f};
        for (int st = 0; st < 4; ++st) {
            const u16* kp = &Kls[buf][(st * 16 + lr) * 64];
            bf16x8 kf0 = *(const bf16x8*)(kp + swz1);
            bf16x8 kf1 = *(const bf16x8*)(kp + swz2);
            sacc[st] = mfma16(qf0, kf0, sacc[st]);
            sacc[st] = mfma16(qf1, kf1, sacc[st]);
        }
        // scale + causal mask (diagonal tile only)
        bool diag = (kt == qt);
        for (int st = 0; st < 4; ++st)
            for (int r = 0; r < 4; ++r) {
                float v = sacc[st][r] * 0.125f;
                if (diag && (kt * 64 + st * 16 + lr) > (qrow + quad * 4 + r)) v = -INFINITY;
                sacc[st][r] = v;
            }
        // online softmax per row
        float alpha[4];
        for (int r = 0; r < 4; ++r) {
            float v = fmaxf(fmaxf(sacc[0][r], sacc[1][r]), fmaxf(sacc[2][r], sacc[3][r]));
            for (int off = 8; off >= 1; off >>= 1) v = fmaxf(v, __shfl_xor(v, off, 16));
            float nm = fmaxf(mrow[r], v);
            alpha[r] = __expf(mrow[r] - nm);
            mrow[r] = nm;
            float rs = 0.f;
            for (int st = 0; st < 4; ++st) {
                float p = __expf(sacc[st][r] - nm);
                sacc[st][r] = p;
                rs += p;
            }
            for (int off = 8; off >= 1; off >>= 1) rs += __shfl_xor(rs, off, 16);
            lrow[r] = lrow[r] * alpha[r] + rs;
        }
        for (int dt = 0; dt < 4; ++dt)
            for (int r = 0; r < 4; ++r) oacc[dt][r] *= alpha[r];
        // P (C-layout) -> per-wave LDS (swizzled) -> reread in A-layout
        for (int st = 0; st < 4; ++st)
            for (int r = 0; r < 4; ++r) {
                int row = quad * 4 + r;
                int gl = st * 2 + (lr >> 3);
                pl[row * 64 + ((gl ^ (row & 7)) * 8) + (lr & 7)] = f2bf(sacc[st][r]);
            }
        bf16x8 ap0 = *(const bf16x8*)&pl[lr * 64 + swz1];
        bf16x8 ap1 = *(const bf16x8*)&pl[lr * 64 + swz2];
        // O += P V
        for (int dt = 0; dt < 4; ++dt) {
            const u16* vp = &Vls[buf][(dt * 16 + lr) * 64];
            bf16x8 vf0 = *(const bf16x8*)(vp + swz1);
            bf16x8 vf1 = *(const bf16x8*)(vp + swz2);
            oacc[dt] = mfma16(ap0, vf0, oacc[dt]);
            oacc[dt] = mfma16(ap1, vf1, oacc[dt]);
        }
    }

    // epilogue: Y[b, t, h*64 + d] bf16
    int b = bh >> 4, h = bh & 15;
    for (int r = 0; r < 4; ++r) {
        float inv = 1.0f / lrow[r];
        int tg = qrow + quad * 4 + r;
        for (int dt = 0; dt < 4; ++dt) {
            Y[((size_t)(b * T_ + tg)) * C_ + h * 64 + dt * 16 + lr] = f2bf(oacc[dt][r] * inv);
        }
    }
}

extern "C" void kernel_launch(void* const* d_in, const int* in_sizes, int n_in,
                              void* d_out, int out_size, void* d_ws, size_t ws_size,
                              hipStream_t stream) {
    const float* x      = (const float*)d_in[0];  // [B,T,C]
    const float* w_qkv  = (const float*)d_in[1];  // [C,3C]
    const float* w_proj = (const float*)d_in[2];  // [C,C]
    const float* b_proj = (const float*)d_in[3];  // [C]
    float* out = (float*)d_out;                   // [B,T,C] fp32

    char* ws = (char*)d_ws;
    u16* x_bf    = (u16*)(ws + 0);          // 8 MB
    u16* wqkv_t  = (u16*)(ws + 8388608);    // 6 MB
    u16* wproj_t = (u16*)(ws + 14680064);   // 2 MB
    u16* q_bf    = (u16*)(ws + 16777216);   // 8 MB  [bh][t][d]
    u16* k_bf    = (u16*)(ws + 25165824);   // 8 MB  [bh][t][d]
    u16* vt_bf   = (u16*)(ws + 33554432);   // 8 MB  [bh][d][t]
    u16* y_bf    = (u16*)(ws + 41943040);   // 8 MB  [b*t][c]

    const int M = B_ * T_;  // 4096

    cast_kernel<<<M * C_ / 1024, 256, 0, stream>>>(x, x_bf, M * C_);
    transpose_cast_kernel<<<dim3(3 * C_ / 64, C_ / 64), 256, 0, stream>>>(w_qkv, wqkv_t, C_, 3 * C_);
    transpose_cast_kernel<<<dim3(C_ / 64, C_ / 64), 256, 0, stream>>>(w_proj, wproj_t, C_, C_);

    gemm_bt<1><<<dim3(3 * C_ / 128, M / 128), 256, 0, stream>>>(
        x_bf, wqkv_t, nullptr, q_bf, k_bf, vt_bf, nullptr, M, 3 * C_, C_);

    attn_kernel<<<B_ * H_ * (T_ / 64), 256, 0, stream>>>(q_bf, k_bf, vt_bf, y_bf);

    gemm_bt<2><<<dim3(C_ / 128, M / 128), 256, 0, stream>>>(
        y_bf, wproj_t, out, nullptr, nullptr, nullptr, b_proj, M, C_, C_);
}